// Round 18
// baseline (240.986 us; speedup 1.0000x reference)
//
#include <hip/hip_runtime.h>

#define NNODES 100000
#define NEDGES 1600000
#define DIM    128

#define NPB    32                              // nodes per bin (dst>>5)
#define NBINS  ((NNODES + NPB - 1) / NPB)      // 3125 (exact)
#define ECHUNK2 4096
#define NBLK2  ((NEDGES + ECHUNK2 - 1) / ECHUNK2)   // 391

#define SRCMASK 0x1FFFFu                       // 17 bits; NNODES < 2^17
#define BCHUNK  1024                           // records per LDS chunk

typedef short  bf16x8 __attribute__((ext_vector_type(8)));
typedef float  f32x4  __attribute__((ext_vector_type(4)));

// ===================== fp32 -> bf16 convert (RNE), 8 elems/thread ===========
__global__ __launch_bounds__(256)
void cvt_f32_bf16(const float* __restrict__ src, unsigned short* __restrict__ dst,
                  int n8)
{
    int i = blockIdx.x * 256 + threadIdx.x;
    if (i >= n8) return;
    const float4* s = reinterpret_cast<const float4*>(src) + (size_t)i * 2;
    float4 a = s[0], b = s[1];
    float v[8] = {a.x, a.y, a.z, a.w, b.x, b.y, b.z, b.w};
    unsigned short r[8];
    #pragma unroll
    for (int j = 0; j < 8; ++j) {
        unsigned u = __float_as_uint(v[j]);
        r[j] = (unsigned short)((u + 0x7FFFu + ((u >> 16) & 1u)) >> 16);
    }
    reinterpret_cast<uint4*>(dst)[i] = *reinterpret_cast<uint4*>(r);
}

// ============== atomic-free CSR build: LDS-histogram counting sort ==========
// Pass 1: per-block LDS bin histogram -> H[b][bin] (coalesced row write).
__global__ __launch_bounds__(256)
void gnn_binhist_lds(const int* __restrict__ edst, int* __restrict__ Hm)
{
    __shared__ int lh[NBINS];
    int b = blockIdx.x;
    for (int i = threadIdx.x; i < NBINS; i += 256) lh[i] = 0;
    __syncthreads();
    int base = b * ECHUNK2;
    int n = NEDGES - base; if (n > ECHUNK2) n = ECHUNK2;
    for (int i = threadIdx.x; i < n; i += 256)
        atomicAdd(&lh[edst[base + i] >> 5], 1);
    __syncthreads();
    for (int i = threadIdx.x; i < NBINS; i += 256)
        Hm[(size_t)b * NBINS + i] = lh[i];
}

// S1: column scan over blocks (thread = bin).
__global__ __launch_bounds__(256)
void gnn_scan_cols(int* __restrict__ Hm, int* __restrict__ btot)
{
    int bin = blockIdx.x * 256 + threadIdx.x;
    if (bin >= NBINS) return;
    int run = 0;
    for (int b = 0; b < NBLK2; ++b) {
        size_t idx = (size_t)b * NBINS + bin;
        int t = Hm[idx];
        Hm[idx] = run;
        run += t;
    }
    btot[bin] = run;
}

// S2: serial scan of 3125 bin totals -> binoff.
__global__ void gnn_binoff_scan(const int* __restrict__ btot,
                                int* __restrict__ binoff)
{
    if (threadIdx.x == 0 && blockIdx.x == 0) {
        int run = 0;
        for (int i = 0; i < NBINS; ++i) { binoff[i] = run; run += btot[i]; }
        binoff[NBINS] = run;
    }
}

// Pass 2: scatter FULL records uint2{dstlocal<<17|src, w} via LDS cursors.
// Each (block, bin) output range is private; zero global atomics.
__global__ __launch_bounds__(256)
void gnn_binscatter_lds(const int* __restrict__ esrc, const int* __restrict__ edst,
                        const float* __restrict__ ew, const int* __restrict__ Hm,
                        const int* __restrict__ binoff,
                        uint2* __restrict__ binbuf)
{
    __shared__ int lcur[NBINS];
    int b = blockIdx.x;
    for (int i = threadIdx.x; i < NBINS; i += 256)
        lcur[i] = binoff[i] + Hm[(size_t)b * NBINS + i];
    __syncthreads();
    int base = b * ECHUNK2;
    int n = NEDGES - base; if (n > ECHUNK2) n = ECHUNK2;
    for (int i = threadIdx.x; i < n; i += 256) {
        int e = base + i;
        int d = edst[e];
        int pos = atomicAdd(&lcur[d >> 5], 1);
        uint2 rec;
        rec.x = ((unsigned)(d & 31) << 17) | (unsigned)esrc[e];
        rec.y = __float_as_uint(ew[e]);
        binbuf[pos] = rec;
    }
}

// ====== FUSED binsort + gather-reduce (mean): one block per bin =============
// NPB=32 -> 3125 blocks (12.2/CU) for load balance + occupancy; R16 two-buffer
// structure at BCHUNK=1024 -> 16.5 KB LDS -> thread-cap (8 blocks/CU) reachable.
// Each 16-lane group owns 2 nodes.
__global__ __launch_bounds__(256)
void gnn_binsort_gather(const uint2* __restrict__ binbuf,
                        const int* __restrict__ binoff,
                        const unsigned short* __restrict__ feat_bf,
                        unsigned short* __restrict__ h_bf)
{
    __shared__ uint2 raw[BCHUNK];     // 8 KB
    __shared__ uint2 srt[BCHUNK];     // 8 KB
    __shared__ int lbase[NPB], ccnt[NPB], lcur[NPB], ltot[NPB];

    int b   = blockIdx.x;
    int tid = threadIdx.x;
    int s = binoff[b], t = binoff[b + 1];

    int g    = tid >> 4;              // 16 groups of 16 lanes
    int lane = tid & 15;

    if (tid < NPB) ltot[tid] = 0;

    float acc[2][8];                  // group's 2 nodes x 8 cols
    #pragma unroll
    for (int a = 0; a < 2; ++a)
        #pragma unroll
        for (int j = 0; j < 8; ++j) acc[a][j] = 0.f;

#define ACCUM(A, P, WW)                                                     \
    {                                                                       \
        unsigned wds[4] = {(P).x, (P).y, (P).z, (P).w};                     \
        _Pragma("unroll")                                                   \
        for (int m = 0; m < 4; ++m) {                                       \
            float lo = __uint_as_float(wds[m] << 16);                       \
            float hi = __uint_as_float(wds[m] & 0xFFFF0000u);               \
            acc[A][2 * m + 0] = fmaf(lo, (WW), acc[A][2 * m + 0]);          \
            acc[A][2 * m + 1] = fmaf(hi, (WW), acc[A][2 * m + 1]);          \
        }                                                                   \
    }

    for (int cs = s; cs < t; cs += BCHUNK) {
        int n = t - cs; if (n > BCHUNK) n = BCHUNK;

        for (int i = tid; i < n; i += 256) raw[i] = binbuf[cs + i];
        if (tid < NPB) lcur[tid] = 0;
        __syncthreads();                       // prev gather done; staging ready

        for (int i = tid; i < n; i += 256)
            atomicAdd(&lcur[raw[i].x >> 17], 1);
        __syncthreads();

        if (tid < NPB) {                       // lanes 0..31 of wave 0: shfl scan
            int v    = lcur[tid];
            int incl = v;
            #pragma unroll
            for (int d = 1; d < 32; d <<= 1) {
                int x = __shfl_up(incl, d, 32);
                if (tid >= d) incl += x;
            }
            int excl = incl - v;
            lbase[tid] = excl;
            ccnt[tid]  = v;
            lcur[tid]  = excl;
            ltot[tid] += v;
        }
        __syncthreads();

        for (int i = tid; i < n; i += 256) {
            uint2 rec = raw[i];
            int pos = atomicAdd(&lcur[rec.x >> 17], 1);
            srt[pos] = rec;
        }
        __syncthreads();

        // gather: group g owns nodes 2g, 2g+1 (contiguous segments)
        #pragma unroll
        for (int a = 0; a < 2; ++a) {
            int nl = g * 2 + a;
            int e  = lbase[nl];
            int e1 = e + ccnt[nl];
            for (; e + 3 < e1; e += 4) {
                uint2 r0 = srt[e],     r1 = srt[e + 1];
                uint2 r2 = srt[e + 2], r3 = srt[e + 3];
                uint4 p0 = reinterpret_cast<const uint4*>(
                    feat_bf + (size_t)(r0.x & SRCMASK) * DIM)[lane];
                uint4 p1 = reinterpret_cast<const uint4*>(
                    feat_bf + (size_t)(r1.x & SRCMASK) * DIM)[lane];
                uint4 p2 = reinterpret_cast<const uint4*>(
                    feat_bf + (size_t)(r2.x & SRCMASK) * DIM)[lane];
                uint4 p3 = reinterpret_cast<const uint4*>(
                    feat_bf + (size_t)(r3.x & SRCMASK) * DIM)[lane];
                ACCUM(a, p0, __uint_as_float(r0.y))
                ACCUM(a, p1, __uint_as_float(r1.y))
                ACCUM(a, p2, __uint_as_float(r2.y))
                ACCUM(a, p3, __uint_as_float(r3.y))
            }
            for (; e < e1; ++e) {
                uint2 r0 = srt[e];
                uint4 p0 = reinterpret_cast<const uint4*>(
                    feat_bf + (size_t)(r0.x & SRCMASK) * DIM)[lane];
                ACCUM(a, p0, __uint_as_float(r0.y))
            }
        }
        __syncthreads();                       // raw/srt reuse next chunk
    }
#undef ACCUM

    // epilogue: mean -> bf16 -> h_bf (coalesced 256B per node row)
    #pragma unroll
    for (int a = 0; a < 2; ++a) {
        int nl   = g * 2 + a;
        int node = b * NPB + nl;
        if (node >= NNODES) continue;
        float inv = 1.0f / fmaxf((float)ltot[nl], 1.0f);
        unsigned short r[8];
        #pragma unroll
        for (int j = 0; j < 8; ++j) {
            unsigned u = __float_as_uint(acc[a][j] * inv);
            r[j] = (unsigned short)((u + 0x7FFFu + ((u >> 16) & 1u)) >> 16);
        }
        reinterpret_cast<uint4*>(h_bf + (size_t)node * DIM)[lane] =
            *reinterpret_cast<uint4*>(r);
    }
}

// ============== Linear + bias + ReLU via bf16 MFMA ==========================
__global__ __launch_bounds__(256)
void gnn_linear_mfma(const unsigned short* __restrict__ h_bf,
                     const unsigned short* __restrict__ W_bf,
                     const float* __restrict__ bias,
                     float* __restrict__ out)
{
    int wave  = threadIdx.x >> 6;
    int lane  = threadIdx.x & 63;
    int tile  = blockIdx.x * 4 + wave;
    int rbase = tile * 16;
    if (rbase >= NNODES) return;

    int r  = lane & 15;
    int kh = lane >> 4;                 // 0..3
    int row = rbase + r;

    bf16x8 afrag[4];
    #pragma unroll
    for (int kk = 0; kk < 4; ++kk)
        afrag[kk] = *reinterpret_cast<const bf16x8*>(
            h_bf + (size_t)row * DIM + kk * 32 + kh * 8);

    #pragma unroll
    for (int jt = 0; jt < 8; ++jt) {
        int col = jt * 16 + r;
        f32x4 acc = {0.f, 0.f, 0.f, 0.f};
        #pragma unroll
        for (int kk = 0; kk < 4; ++kk) {
            bf16x8 bfrag = *reinterpret_cast<const bf16x8*>(
                W_bf + (size_t)col * DIM + kk * 32 + kh * 8);
            acc = __builtin_amdgcn_mfma_f32_16x16x32_bf16(afrag[kk], bfrag, acc, 0, 0, 0);
        }
        float bc = bias[col];
        #pragma unroll
        for (int rg = 0; rg < 4; ++rg) {
            int orow = rbase + kh * 4 + rg;
            out[(size_t)orow * DIM + col] = fmaxf(acc[rg] + bc, 0.f);
        }
    }
}

// ======== fallback fp32 path (ws too small for bf16 buffers) ================
__global__ __launch_bounds__(256)
void gnn_agg(const float* __restrict__ feature,
             const int*   __restrict__ esrc,
             const int*   __restrict__ edst,
             const float* __restrict__ ew,
             float*       __restrict__ agg,
             float*       __restrict__ cnt)
{
    int gid  = blockIdx.x * 256 + threadIdx.x;
    int e    = gid >> 5;
    int lane = gid & 31;
    if (e >= NEDGES) return;
    int   s = esrc[e];
    int   d = edst[e];
    float w = ew[e];
    float4 v = reinterpret_cast<const float4*>(feature + (size_t)s * DIM)[lane];
    float* arow = agg + (size_t)d * DIM + lane * 4;
    atomicAdd(arow + 0, v.x * w);
    atomicAdd(arow + 1, v.y * w);
    atomicAdd(arow + 2, v.z * w);
    atomicAdd(arow + 3, v.w * w);
    if (lane == 0) atomicAdd(cnt + d, 1.0f);
}

__global__ __launch_bounds__(256)
void gnn_linear(float*       __restrict__ h,
                const float* __restrict__ cnt,
                const float* __restrict__ W,
                const float* __restrict__ bias)
{
    __shared__ float Wt[DIM][DIM];
    for (int i = threadIdx.x; i < DIM * DIM; i += 256) {
        int j = i >> 7, k = i & 127;
        Wt[k][j] = W[i];
    }
    __syncthreads();

    int grp   = threadIdx.x >> 5;
    int lane  = threadIdx.x & 31;
    int node0 = blockIdx.x * 32 + grp * 4;

    const float4* h0 = reinterpret_cast<const float4*>(h + (size_t)(node0 + 0) * DIM);
    const float4* h1 = reinterpret_cast<const float4*>(h + (size_t)(node0 + 1) * DIM);
    const float4* h2 = reinterpret_cast<const float4*>(h + (size_t)(node0 + 2) * DIM);
    const float4* h3 = reinterpret_cast<const float4*>(h + (size_t)(node0 + 3) * DIM);

    float4 acc0 = {0.f, 0.f, 0.f, 0.f};
    float4 acc1 = acc0, acc2 = acc0, acc3 = acc0;

    for (int k4 = 0; k4 < DIM / 4; ++k4) {
        float4 x0 = h0[k4];
        float4 x1 = h1[k4];
        float4 x2 = h2[k4];
        float4 x3 = h3[k4];
#define STEP(KK, COMP)                                                          \
        {                                                                       \
            float4 wv = *reinterpret_cast<const float4*>(&Wt[k4 * 4 + KK][lane * 4]); \
            acc0.x = fmaf(x0.COMP, wv.x, acc0.x);                               \
            acc0.y = fmaf(x0.COMP, wv.y, acc0.y);                               \
            acc0.z = fmaf(x0.COMP, wv.z, acc0.z);                               \
            acc0.w = fmaf(x0.COMP, wv.w, acc0.w);                               \
            acc1.x = fmaf(x1.COMP, wv.x, acc1.x);                               \
            acc1.y = fmaf(x1.COMP, wv.y, acc1.y);                               \
            acc1.z = fmaf(x1.COMP, wv.z, acc1.z);                               \
            acc1.w = fmaf(x1.COMP, wv.w, acc1.w);                               \
            acc2.x = fmaf(x2.COMP, wv.x, acc2.x);                               \
            acc2.y = fmaf(x2.COMP, wv.y, acc2.y);                               \
            acc2.z = fmaf(x2.COMP, wv.z, acc2.z);                               \
            acc2.w = fmaf(x2.COMP, wv.w, acc2.w);                               \
            acc3.x = fmaf(x3.COMP, wv.x, acc3.x);                               \
            acc3.y = fmaf(x3.COMP, wv.y, acc3.y);                               \
            acc3.z = fmaf(x3.COMP, wv.z, acc3.z);                               \
            acc3.w = fmaf(x3.COMP, wv.w, acc3.w);                               \
        }
        STEP(0, x) STEP(1, y) STEP(2, z) STEP(3, w)
#undef STEP
    }

    float4 bv = *reinterpret_cast<const float4*>(bias + lane * 4);
    float inv0 = 1.f, inv1 = 1.f, inv2 = 1.f, inv3 = 1.f;
    if (cnt) {
        inv0 = 1.0f / fmaxf(cnt[node0 + 0], 1.0f);
        inv1 = 1.0f / fmaxf(cnt[node0 + 1], 1.0f);
        inv2 = 1.0f / fmaxf(cnt[node0 + 2], 1.0f);
        inv3 = 1.0f / fmaxf(cnt[node0 + 3], 1.0f);
    }

    float4 r0, r1, r2, r3;
    r0.x = fmaxf(fmaf(acc0.x, inv0, bv.x), 0.f);
    r0.y = fmaxf(fmaf(acc0.y, inv0, bv.y), 0.f);
    r0.z = fmaxf(fmaf(acc0.z, inv0, bv.z), 0.f);
    r0.w = fmaxf(fmaf(acc0.w, inv0, bv.w), 0.f);
    r1.x = fmaxf(fmaf(acc1.x, inv1, bv.x), 0.f);
    r1.y = fmaxf(fmaf(acc1.y, inv1, bv.y), 0.f);
    r1.z = fmaxf(fmaf(acc1.z, inv1, bv.z), 0.f);
    r1.w = fmaxf(fmaf(acc1.w, inv1, bv.w), 0.f);
    r2.x = fmaxf(fmaf(acc2.x, inv2, bv.x), 0.f);
    r2.y = fmaxf(fmaf(acc2.y, inv2, bv.y), 0.f);
    r2.z = fmaxf(fmaf(acc2.z, inv2, bv.z), 0.f);
    r2.w = fmaxf(fmaf(acc2.w, inv2, bv.w), 0.f);
    r3.x = fmaxf(fmaf(acc3.x, inv3, bv.x), 0.f);
    r3.y = fmaxf(fmaf(acc3.y, inv3, bv.y), 0.f);
    r3.z = fmaxf(fmaf(acc3.z, inv3, bv.z), 0.f);
    r3.w = fmaxf(fmaf(acc3.w, inv3, bv.w), 0.f);

    reinterpret_cast<float4*>(h + (size_t)(node0 + 0) * DIM)[lane] = r0;
    reinterpret_cast<float4*>(h + (size_t)(node0 + 1) * DIM)[lane] = r1;
    reinterpret_cast<float4*>(h + (size_t)(node0 + 2) * DIM)[lane] = r2;
    reinterpret_cast<float4*>(h + (size_t)(node0 + 3) * DIM)[lane] = r3;
}

// ============================================================================

extern "C" void kernel_launch(void* const* d_in, const int* in_sizes, int n_in,
                              void* d_out, int out_size, void* d_ws, size_t ws_size,
                              hipStream_t stream)
{
    const float* feature = (const float*)d_in[0];
    const int*   esrc    = (const int*)  d_in[1];
    const int*   edst    = (const int*)  d_in[2];
    const float* ew      = (const float*)d_in[3];
    const float* W       = (const float*)d_in[4];
    const float* bias    = (const float*)d_in[5];
    float* out = (float*)d_out;

    char* ws = (char*)d_ws;
    const size_t A = 255;
    size_t binoff_b = 0;
    size_t btot_b   = binoff_b + (((size_t)(NBINS + 1) * 4 + A) & ~A);
    size_t bbuf_b   = btot_b   + (((size_t)NBINS * 4 + A) & ~A);
    size_t featb_b  = bbuf_b   + (((size_t)NEDGES * 8 + A) & ~A);
    size_t hb_b     = featb_b  + (((size_t)NNODES * DIM * 2 + A) & ~A);
    size_t wb_b     = hb_b     + (((size_t)NNODES * DIM * 2 + A) & ~A);
    size_t need_bf  = wb_b     + (size_t)DIM * DIM * 2;
    // alias (disjoint lifetimes): Hm (NBLK2*NBINS*4 = 4.89 MB) -> h_bf region
    // (Hm dead after binscatter; h_bf written only by binsort_gather after).
    // binbuf has its OWN region: read while h_bf is written.

    if (ws_size >= need_bf) {
        int*            binoff  = (int*)           (ws + binoff_b);
        int*            btot    = (int*)           (ws + btot_b);
        uint2*          binbuf  = (uint2*)         (ws + bbuf_b);
        unsigned short* feat_bf = (unsigned short*)(ws + featb_b);
        unsigned short* h_bf    = (unsigned short*)(ws + hb_b);
        int*            Hm      = (int*)           (ws + hb_b);     // alias
        unsigned short* W_bf    = (unsigned short*)(ws + wb_b);

        cvt_f32_bf16<<<(NNODES * DIM / 8 + 255) / 256, 256, 0, stream>>>(
            feature, feat_bf, NNODES * DIM / 8);
        cvt_f32_bf16<<<(DIM * DIM / 8 + 255) / 256, 256, 0, stream>>>(
            W, W_bf, DIM * DIM / 8);
        gnn_binhist_lds<<<NBLK2, 256, 0, stream>>>(edst, Hm);
        gnn_scan_cols<<<(NBINS + 255) / 256, 256, 0, stream>>>(Hm, btot);
        gnn_binoff_scan<<<1, 64, 0, stream>>>(btot, binoff);
        gnn_binscatter_lds<<<NBLK2, 256, 0, stream>>>(esrc, edst, ew, Hm,
                                                      binoff, binbuf);
        gnn_binsort_gather<<<NBINS, 256, 0, stream>>>(binbuf, binoff,
                                                      feat_bf, h_bf);
        gnn_linear_mfma<<<(NNODES / 16 + 3) / 4, 256, 0, stream>>>(h_bf, W_bf,
                                                                   bias, out);
    } else {
        float* cntf = (float*)d_ws;
        hipMemsetAsync(out,  0, (size_t)NNODES * DIM * sizeof(float), stream);
        hipMemsetAsync(cntf, 0, (size_t)NNODES * sizeof(float), stream);
        gnn_agg<<<(NEDGES * 32 + 255) / 256, 256, 0, stream>>>(feature, esrc, edst,
                                                               ew, out, cntf);
        gnn_linear<<<NNODES / 32, 256, 0, stream>>>(out, cntf, W, bias);
    }
}

// Round 19
// 161.965 us; speedup vs baseline: 1.4879x; 1.4879x over previous
//
#include <hip/hip_runtime.h>

#define NNODES 100000
#define NEDGES 1600000
#define DIM    128

#define NPB    32                              // nodes per bin (dst>>5)
#define NBINS  ((NNODES + NPB - 1) / NPB)      // 3125 (exact)
#define ECHUNK2 4096
#define NBLK2  ((NEDGES + ECHUNK2 - 1) / ECHUNK2)   // 391

#define SRCMASK 0x1FFFFu                       // 17 bits; NNODES < 2^17
#define BCHUNK  1024                           // records per LDS chunk

typedef short  bf16x8 __attribute__((ext_vector_type(8)));
typedef float  f32x4  __attribute__((ext_vector_type(4)));

// ===================== fp32 -> bf16 convert (RNE), 8 elems/thread ===========
__global__ __launch_bounds__(256)
void cvt_f32_bf16(const float* __restrict__ src, unsigned short* __restrict__ dst,
                  int n8)
{
    int i = blockIdx.x * 256 + threadIdx.x;
    if (i >= n8) return;
    const float4* s = reinterpret_cast<const float4*>(src) + (size_t)i * 2;
    float4 a = s[0], b = s[1];
    float v[8] = {a.x, a.y, a.z, a.w, b.x, b.y, b.z, b.w};
    unsigned short r[8];
    #pragma unroll
    for (int j = 0; j < 8; ++j) {
        unsigned u = __float_as_uint(v[j]);
        r[j] = (unsigned short)((u + 0x7FFFu + ((u >> 16) & 1u)) >> 16);
    }
    reinterpret_cast<uint4*>(dst)[i] = *reinterpret_cast<uint4*>(r);
}

// ============== atomic-free CSR build: LDS-histogram counting sort ==========
// Pass 1: per-block LDS bin histogram -> H[b][bin] (coalesced row write).
__global__ __launch_bounds__(256)
void gnn_binhist_lds(const int* __restrict__ edst, int* __restrict__ Hm)
{
    __shared__ int lh[NBINS];
    int b = blockIdx.x;
    for (int i = threadIdx.x; i < NBINS; i += 256) lh[i] = 0;
    __syncthreads();
    int base = b * ECHUNK2;
    int n = NEDGES - base; if (n > ECHUNK2) n = ECHUNK2;
    for (int i = threadIdx.x; i < n; i += 256)
        atomicAdd(&lh[edst[base + i] >> 5], 1);
    __syncthreads();
    for (int i = threadIdx.x; i < NBINS; i += 256)
        Hm[(size_t)b * NBINS + i] = lh[i];
}

// S1: column scan over blocks (thread = bin).
__global__ __launch_bounds__(256)
void gnn_scan_cols(int* __restrict__ Hm, int* __restrict__ btot)
{
    int bin = blockIdx.x * 256 + threadIdx.x;
    if (bin >= NBINS) return;
    int run = 0;
    for (int b = 0; b < NBLK2; ++b) {
        size_t idx = (size_t)b * NBINS + bin;
        int t = Hm[idx];
        Hm[idx] = run;
        run += t;
    }
    btot[bin] = run;
}

// S2: PARALLEL single-block scan of 3125 bin totals -> binoff.
// (R18's serial version was 84 us — 3125 dependent L2 round-trips.)
__global__ __launch_bounds__(1024)
void gnn_binoff_scan_par(const int* __restrict__ btot, int* __restrict__ binoff)
{
    __shared__ int wsum[16];
    int t = threadIdx.x;
    int running = 0;
    for (int base = 0; base < NBINS; base += 1024) {
        int i = base + t;
        int v = (i < NBINS) ? btot[i] : 0;
        int incl = v;
        #pragma unroll
        for (int d = 1; d < 64; d <<= 1) {
            int x = __shfl_up(incl, d, 64);
            if ((t & 63) >= d) incl += x;
        }
        int wid = t >> 6;
        if ((t & 63) == 63) wsum[wid] = incl;
        __syncthreads();
        if (t < 16) {
            int ws = wsum[t];
            #pragma unroll
            for (int d = 1; d < 16; d <<= 1) {
                int x = __shfl_up(ws, d, 16);
                if (t >= d) ws += x;
            }
            wsum[t] = ws;
        }
        __syncthreads();
        int wprefix = (wid > 0) ? wsum[wid - 1] : 0;
        int chunk_total = wsum[15];
        int excl = running + wprefix + (incl - v);
        if (i < NBINS) binoff[i] = excl;
        running += chunk_total;
        __syncthreads();
    }
    if (t == 0) binoff[NBINS] = running;
}

// Pass 2: scatter FULL records uint2{dstlocal<<17|src, w} via LDS cursors.
// Each (block, bin) output range is private; zero global atomics.
__global__ __launch_bounds__(256)
void gnn_binscatter_lds(const int* __restrict__ esrc, const int* __restrict__ edst,
                        const float* __restrict__ ew, const int* __restrict__ Hm,
                        const int* __restrict__ binoff,
                        uint2* __restrict__ binbuf)
{
    __shared__ int lcur[NBINS];
    int b = blockIdx.x;
    for (int i = threadIdx.x; i < NBINS; i += 256)
        lcur[i] = binoff[i] + Hm[(size_t)b * NBINS + i];
    __syncthreads();
    int base = b * ECHUNK2;
    int n = NEDGES - base; if (n > ECHUNK2) n = ECHUNK2;
    for (int i = threadIdx.x; i < n; i += 256) {
        int e = base + i;
        int d = edst[e];
        int pos = atomicAdd(&lcur[d >> 5], 1);
        uint2 rec;
        rec.x = ((unsigned)(d & 31) << 17) | (unsigned)esrc[e];
        rec.y = __float_as_uint(ew[e]);
        binbuf[pos] = rec;
    }
}

// ====== FUSED binsort + gather-reduce (mean): one block per bin =============
// NPB=32 -> 3125 blocks; two-buffer structure at BCHUNK=1024 (16.5 KB LDS).
// Each 16-lane group owns 2 nodes.
__global__ __launch_bounds__(256)
void gnn_binsort_gather(const uint2* __restrict__ binbuf,
                        const int* __restrict__ binoff,
                        const unsigned short* __restrict__ feat_bf,
                        unsigned short* __restrict__ h_bf)
{
    __shared__ uint2 raw[BCHUNK];     // 8 KB
    __shared__ uint2 srt[BCHUNK];     // 8 KB
    __shared__ int lbase[NPB], ccnt[NPB], lcur[NPB], ltot[NPB];

    int b   = blockIdx.x;
    int tid = threadIdx.x;
    int s = binoff[b], t = binoff[b + 1];

    int g    = tid >> 4;              // 16 groups of 16 lanes
    int lane = tid & 15;

    if (tid < NPB) ltot[tid] = 0;

    float acc[2][8];                  // group's 2 nodes x 8 cols
    #pragma unroll
    for (int a = 0; a < 2; ++a)
        #pragma unroll
        for (int j = 0; j < 8; ++j) acc[a][j] = 0.f;

#define ACCUM(A, P, WW)                                                     \
    {                                                                       \
        unsigned wds[4] = {(P).x, (P).y, (P).z, (P).w};                     \
        _Pragma("unroll")                                                   \
        for (int m = 0; m < 4; ++m) {                                       \
            float lo = __uint_as_float(wds[m] << 16);                       \
            float hi = __uint_as_float(wds[m] & 0xFFFF0000u);               \
            acc[A][2 * m + 0] = fmaf(lo, (WW), acc[A][2 * m + 0]);          \
            acc[A][2 * m + 1] = fmaf(hi, (WW), acc[A][2 * m + 1]);          \
        }                                                                   \
    }

    for (int cs = s; cs < t; cs += BCHUNK) {
        int n = t - cs; if (n > BCHUNK) n = BCHUNK;

        for (int i = tid; i < n; i += 256) raw[i] = binbuf[cs + i];
        if (tid < NPB) lcur[tid] = 0;
        __syncthreads();                       // prev gather done; staging ready

        for (int i = tid; i < n; i += 256)
            atomicAdd(&lcur[raw[i].x >> 17], 1);
        __syncthreads();

        if (tid < NPB) {                       // lanes 0..31 of wave 0: shfl scan
            int v    = lcur[tid];
            int incl = v;
            #pragma unroll
            for (int d = 1; d < 32; d <<= 1) {
                int x = __shfl_up(incl, d, 32);
                if (tid >= d) incl += x;
            }
            int excl = incl - v;
            lbase[tid] = excl;
            ccnt[tid]  = v;
            lcur[tid]  = excl;
            ltot[tid] += v;
        }
        __syncthreads();

        for (int i = tid; i < n; i += 256) {
            uint2 rec = raw[i];
            int pos = atomicAdd(&lcur[rec.x >> 17], 1);
            srt[pos] = rec;
        }
        __syncthreads();

        // gather: group g owns nodes 2g, 2g+1 (contiguous segments)
        #pragma unroll
        for (int a = 0; a < 2; ++a) {
            int nl = g * 2 + a;
            int e  = lbase[nl];
            int e1 = e + ccnt[nl];
            for (; e + 3 < e1; e += 4) {
                uint2 r0 = srt[e],     r1 = srt[e + 1];
                uint2 r2 = srt[e + 2], r3 = srt[e + 3];
                uint4 p0 = reinterpret_cast<const uint4*>(
                    feat_bf + (size_t)(r0.x & SRCMASK) * DIM)[lane];
                uint4 p1 = reinterpret_cast<const uint4*>(
                    feat_bf + (size_t)(r1.x & SRCMASK) * DIM)[lane];
                uint4 p2 = reinterpret_cast<const uint4*>(
                    feat_bf + (size_t)(r2.x & SRCMASK) * DIM)[lane];
                uint4 p3 = reinterpret_cast<const uint4*>(
                    feat_bf + (size_t)(r3.x & SRCMASK) * DIM)[lane];
                ACCUM(a, p0, __uint_as_float(r0.y))
                ACCUM(a, p1, __uint_as_float(r1.y))
                ACCUM(a, p2, __uint_as_float(r2.y))
                ACCUM(a, p3, __uint_as_float(r3.y))
            }
            for (; e < e1; ++e) {
                uint2 r0 = srt[e];
                uint4 p0 = reinterpret_cast<const uint4*>(
                    feat_bf + (size_t)(r0.x & SRCMASK) * DIM)[lane];
                ACCUM(a, p0, __uint_as_float(r0.y))
            }
        }
        __syncthreads();                       // raw/srt reuse next chunk
    }
#undef ACCUM

    // epilogue: mean -> bf16 -> h_bf (coalesced 256B per node row)
    #pragma unroll
    for (int a = 0; a < 2; ++a) {
        int nl   = g * 2 + a;
        int node = b * NPB + nl;
        if (node >= NNODES) continue;
        float inv = 1.0f / fmaxf((float)ltot[nl], 1.0f);
        unsigned short r[8];
        #pragma unroll
        for (int j = 0; j < 8; ++j) {
            unsigned u = __float_as_uint(acc[a][j] * inv);
            r[j] = (unsigned short)((u + 0x7FFFu + ((u >> 16) & 1u)) >> 16);
        }
        reinterpret_cast<uint4*>(h_bf + (size_t)node * DIM)[lane] =
            *reinterpret_cast<uint4*>(r);
    }
}

// ============== Linear + bias + ReLU via bf16 MFMA ==========================
__global__ __launch_bounds__(256)
void gnn_linear_mfma(const unsigned short* __restrict__ h_bf,
                     const unsigned short* __restrict__ W_bf,
                     const float* __restrict__ bias,
                     float* __restrict__ out)
{
    int wave  = threadIdx.x >> 6;
    int lane  = threadIdx.x & 63;
    int tile  = blockIdx.x * 4 + wave;
    int rbase = tile * 16;
    if (rbase >= NNODES) return;

    int r  = lane & 15;
    int kh = lane >> 4;                 // 0..3
    int row = rbase + r;

    bf16x8 afrag[4];
    #pragma unroll
    for (int kk = 0; kk < 4; ++kk)
        afrag[kk] = *reinterpret_cast<const bf16x8*>(
            h_bf + (size_t)row * DIM + kk * 32 + kh * 8);

    #pragma unroll
    for (int jt = 0; jt < 8; ++jt) {
        int col = jt * 16 + r;
        f32x4 acc = {0.f, 0.f, 0.f, 0.f};
        #pragma unroll
        for (int kk = 0; kk < 4; ++kk) {
            bf16x8 bfrag = *reinterpret_cast<const bf16x8*>(
                W_bf + (size_t)col * DIM + kk * 32 + kh * 8);
            acc = __builtin_amdgcn_mfma_f32_16x16x32_bf16(afrag[kk], bfrag, acc, 0, 0, 0);
        }
        float bc = bias[col];
        #pragma unroll
        for (int rg = 0; rg < 4; ++rg) {
            int orow = rbase + kh * 4 + rg;
            out[(size_t)orow * DIM + col] = fmaxf(acc[rg] + bc, 0.f);
        }
    }
}

// ======== fallback fp32 path (ws too small for bf16 buffers) ================
__global__ __launch_bounds__(256)
void gnn_agg(const float* __restrict__ feature,
             const int*   __restrict__ esrc,
             const int*   __restrict__ edst,
             const float* __restrict__ ew,
             float*       __restrict__ agg,
             float*       __restrict__ cnt)
{
    int gid  = blockIdx.x * 256 + threadIdx.x;
    int e    = gid >> 5;
    int lane = gid & 31;
    if (e >= NEDGES) return;
    int   s = esrc[e];
    int   d = edst[e];
    float w = ew[e];
    float4 v = reinterpret_cast<const float4*>(feature + (size_t)s * DIM)[lane];
    float* arow = agg + (size_t)d * DIM + lane * 4;
    atomicAdd(arow + 0, v.x * w);
    atomicAdd(arow + 1, v.y * w);
    atomicAdd(arow + 2, v.z * w);
    atomicAdd(arow + 3, v.w * w);
    if (lane == 0) atomicAdd(cnt + d, 1.0f);
}

__global__ __launch_bounds__(256)
void gnn_linear(float*       __restrict__ h,
                const float* __restrict__ cnt,
                const float* __restrict__ W,
                const float* __restrict__ bias)
{
    __shared__ float Wt[DIM][DIM];
    for (int i = threadIdx.x; i < DIM * DIM; i += 256) {
        int j = i >> 7, k = i & 127;
        Wt[k][j] = W[i];
    }
    __syncthreads();

    int grp   = threadIdx.x >> 5;
    int lane  = threadIdx.x & 31;
    int node0 = blockIdx.x * 32 + grp * 4;

    const float4* h0 = reinterpret_cast<const float4*>(h + (size_t)(node0 + 0) * DIM);
    const float4* h1 = reinterpret_cast<const float4*>(h + (size_t)(node0 + 1) * DIM);
    const float4* h2 = reinterpret_cast<const float4*>(h + (size_t)(node0 + 2) * DIM);
    const float4* h3 = reinterpret_cast<const float4*>(h + (size_t)(node0 + 3) * DIM);

    float4 acc0 = {0.f, 0.f, 0.f, 0.f};
    float4 acc1 = acc0, acc2 = acc0, acc3 = acc0;

    for (int k4 = 0; k4 < DIM / 4; ++k4) {
        float4 x0 = h0[k4];
        float4 x1 = h1[k4];
        float4 x2 = h2[k4];
        float4 x3 = h3[k4];
#define STEP(KK, COMP)                                                          \
        {                                                                       \
            float4 wv = *reinterpret_cast<const float4*>(&Wt[k4 * 4 + KK][lane * 4]); \
            acc0.x = fmaf(x0.COMP, wv.x, acc0.x);                               \
            acc0.y = fmaf(x0.COMP, wv.y, acc0.y);                               \
            acc0.z = fmaf(x0.COMP, wv.z, acc0.z);                               \
            acc0.w = fmaf(x0.COMP, wv.w, acc0.w);                               \
            acc1.x = fmaf(x1.COMP, wv.x, acc1.x);                               \
            acc1.y = fmaf(x1.COMP, wv.y, acc1.y);                               \
            acc1.z = fmaf(x1.COMP, wv.z, acc1.z);                               \
            acc1.w = fmaf(x1.COMP, wv.w, acc1.w);                               \
            acc2.x = fmaf(x2.COMP, wv.x, acc2.x);                               \
            acc2.y = fmaf(x2.COMP, wv.y, acc2.y);                               \
            acc2.z = fmaf(x2.COMP, wv.z, acc2.z);                               \
            acc2.w = fmaf(x2.COMP, wv.w, acc2.w);                               \
            acc3.x = fmaf(x3.COMP, wv.x, acc3.x);                               \
            acc3.y = fmaf(x3.COMP, wv.y, acc3.y);                               \
            acc3.z = fmaf(x3.COMP, wv.z, acc3.z);                               \
            acc3.w = fmaf(x3.COMP, wv.w, acc3.w);                               \
        }
        STEP(0, x) STEP(1, y) STEP(2, z) STEP(3, w)
#undef STEP
    }

    float4 bv = *reinterpret_cast<const float4*>(bias + lane * 4);
    float inv0 = 1.f, inv1 = 1.f, inv2 = 1.f, inv3 = 1.f;
    if (cnt) {
        inv0 = 1.0f / fmaxf(cnt[node0 + 0], 1.0f);
        inv1 = 1.0f / fmaxf(cnt[node0 + 1], 1.0f);
        inv2 = 1.0f / fmaxf(cnt[node0 + 2], 1.0f);
        inv3 = 1.0f / fmaxf(cnt[node0 + 3], 1.0f);
    }

    float4 r0, r1, r2, r3;
    r0.x = fmaxf(fmaf(acc0.x, inv0, bv.x), 0.f);
    r0.y = fmaxf(fmaf(acc0.y, inv0, bv.y), 0.f);
    r0.z = fmaxf(fmaf(acc0.z, inv0, bv.z), 0.f);
    r0.w = fmaxf(fmaf(acc0.w, inv0, bv.w), 0.f);
    r1.x = fmaxf(fmaf(acc1.x, inv1, bv.x), 0.f);
    r1.y = fmaxf(fmaf(acc1.y, inv1, bv.y), 0.f);
    r1.z = fmaxf(fmaf(acc1.z, inv1, bv.z), 0.f);
    r1.w = fmaxf(fmaf(acc1.w, inv1, bv.w), 0.f);
    r2.x = fmaxf(fmaf(acc2.x, inv2, bv.x), 0.f);
    r2.y = fmaxf(fmaf(acc2.y, inv2, bv.y), 0.f);
    r2.z = fmaxf(fmaf(acc2.z, inv2, bv.z), 0.f);
    r2.w = fmaxf(fmaf(acc2.w, inv2, bv.w), 0.f);
    r3.x = fmaxf(fmaf(acc3.x, inv3, bv.x), 0.f);
    r3.y = fmaxf(fmaf(acc3.y, inv3, bv.y), 0.f);
    r3.z = fmaxf(fmaf(acc3.z, inv3, bv.z), 0.f);
    r3.w = fmaxf(fmaf(acc3.w, inv3, bv.w), 0.f);

    reinterpret_cast<float4*>(h + (size_t)(node0 + 0) * DIM)[lane] = r0;
    reinterpret_cast<float4*>(h + (size_t)(node0 + 1) * DIM)[lane] = r1;
    reinterpret_cast<float4*>(h + (size_t)(node0 + 2) * DIM)[lane] = r2;
    reinterpret_cast<float4*>(h + (size_t)(node0 + 3) * DIM)[lane] = r3;
}

// ============================================================================

extern "C" void kernel_launch(void* const* d_in, const int* in_sizes, int n_in,
                              void* d_out, int out_size, void* d_ws, size_t ws_size,
                              hipStream_t stream)
{
    const float* feature = (const float*)d_in[0];
    const int*   esrc    = (const int*)  d_in[1];
    const int*   edst    = (const int*)  d_in[2];
    const float* ew      = (const float*)d_in[3];
    const float* W       = (const float*)d_in[4];
    const float* bias    = (const float*)d_in[5];
    float* out = (float*)d_out;

    char* ws = (char*)d_ws;
    const size_t A = 255;
    size_t binoff_b = 0;
    size_t btot_b   = binoff_b + (((size_t)(NBINS + 1) * 4 + A) & ~A);
    size_t bbuf_b   = btot_b   + (((size_t)NBINS * 4 + A) & ~A);
    size_t featb_b  = bbuf_b   + (((size_t)NEDGES * 8 + A) & ~A);
    size_t hb_b     = featb_b  + (((size_t)NNODES * DIM * 2 + A) & ~A);
    size_t wb_b     = hb_b     + (((size_t)NNODES * DIM * 2 + A) & ~A);
    size_t need_bf  = wb_b     + (size_t)DIM * DIM * 2;
    // alias (disjoint lifetimes): Hm (NBLK2*NBINS*4 = 4.89 MB) -> h_bf region
    // (Hm dead after binscatter; h_bf written only by binsort_gather after).
    // binbuf has its OWN region: read while h_bf is written.

    if (ws_size >= need_bf) {
        int*            binoff  = (int*)           (ws + binoff_b);
        int*            btot    = (int*)           (ws + btot_b);
        uint2*          binbuf  = (uint2*)         (ws + bbuf_b);
        unsigned short* feat_bf = (unsigned short*)(ws + featb_b);
        unsigned short* h_bf    = (unsigned short*)(ws + hb_b);
        int*            Hm      = (int*)           (ws + hb_b);     // alias
        unsigned short* W_bf    = (unsigned short*)(ws + wb_b);

        cvt_f32_bf16<<<(NNODES * DIM / 8 + 255) / 256, 256, 0, stream>>>(
            feature, feat_bf, NNODES * DIM / 8);
        cvt_f32_bf16<<<(DIM * DIM / 8 + 255) / 256, 256, 0, stream>>>(
            W, W_bf, DIM * DIM / 8);
        gnn_binhist_lds<<<NBLK2, 256, 0, stream>>>(edst, Hm);
        gnn_scan_cols<<<(NBINS + 255) / 256, 256, 0, stream>>>(Hm, btot);
        gnn_binoff_scan_par<<<1, 1024, 0, stream>>>(btot, binoff);
        gnn_binscatter_lds<<<NBLK2, 256, 0, stream>>>(esrc, edst, ew, Hm,
                                                      binoff, binbuf);
        gnn_binsort_gather<<<NBINS, 256, 0, stream>>>(binbuf, binoff,
                                                      feat_bf, h_bf);
        gnn_linear_mfma<<<(NNODES / 16 + 3) / 4, 256, 0, stream>>>(h_bf, W_bf,
                                                                   bias, out);
    } else {
        float* cntf = (float*)d_ws;
        hipMemsetAsync(out,  0, (size_t)NNODES * DIM * sizeof(float), stream);
        hipMemsetAsync(cntf, 0, (size_t)NNODES * sizeof(float), stream);
        gnn_agg<<<(NEDGES * 32 + 255) / 256, 256, 0, stream>>>(feature, esrc, edst,
                                                               ew, out, cntf);
        gnn_linear<<<NNODES / 32, 256, 0, stream>>>(out, cntf, W, bias);
    }
}